// Round 2
// baseline (7719.440 us; speedup 1.0000x reference)
//
#include <hip/hip_runtime.h>

#define CC   184   // cities
#define HLEN 24    // hist_len
#define PLEN 24    // pred_len
#define IND  14    // in_dim
#define DD   15    // in_dim+1 (LSTM0/GRU input dim)
#define HB   32    // hidden
#define BB   512   // batch

__device__ __forceinline__ float sigm(float x)  { return 1.0f / (1.0f + __expf(-x)); }
__device__ __forceinline__ float tanhx(float x) { return 1.0f - 2.0f / (1.0f + __expf(2.0f * x)); }

__global__ __launch_bounds__(256, 2) void bilstm_kernel(
    const float* __restrict__ rain_hist,
    const float* __restrict__ feature,
    const float* __restrict__ h0,
    const float* __restrict__ c0,
    const float* __restrict__ W_mlp,
    const float* __restrict__ b_mlp,
    const float* __restrict__ Wih_g,
    const float* __restrict__ Whh_g,
    const float* __restrict__ b_ih_g,
    const float* __restrict__ b_hh_g,
    const float* __restrict__ Wih0,
    const float* __restrict__ Whh0,
    const float* __restrict__ b0,
    const float* __restrict__ Wih1,
    const float* __restrict__ Whh1,
    const float* __restrict__ b1,
    const float* __restrict__ W_fc,
    const float* __restrict__ b_fc,
    float* __restrict__ out)
{
    const int b   = blockIdx.x;
    const int tid = threadIdx.x;

    __shared__ float xs[CC][16];        // [0]=g, [1]=xn, [2..14]=feat
    __shared__ float y0buf[CC][2*HB];   // layer-0 outputs (fwd 0:32, bwd 32:64)
    __shared__ float hn[4][HB];
    __shared__ float cn[4][HB];
    __shared__ float hcur[2][HB];
    __shared__ float gates[2][4*HB];
    __shared__ float gxbuf[3*HB];
    __shared__ float ghbuf[4][3*HB];
    __shared__ float ubuf[DD];
    __shared__ float xn_lds[CC];

    const int d  = tid >> 7;    // direction for gate threads
    const int gi = tid & 127;   // gate index 0..127 (i,f,g,o x 32)
    const int dd = tid >> 5;    // direction for elementwise threads (tid<64)
    const int kk = tid & 31;    // hidden index for elementwise threads

    // ---- init carried state ----
    for (int idx = tid; idx < 4 * HB; idx += 256) {
        int l = idx >> 5, k = idx & 31;
        hn[l][k] = h0[(l * BB + b) * HB + k];
        cn[l][k] = c0[(l * BB + b) * HB + k];
    }
    for (int c = tid; c < CC; c += 256)
        xs[c][1] = rain_hist[(b * HLEN + (HLEN - 1)) * CC + c];
    __syncthreads();

    float creg = 0.0f;          // cell state (threads 0..63)
    float wreg[64];             // input-weight row (shared between L0/L1 phases)
    float whreg[HB];            // hidden-weight row
    float breg = 0.0f;

    #pragma unroll 1
    for (int t = 0; t < PLEN; ++t) {
        // ---- load this step's features ----
        const float* ft = feature + ((size_t)b * (HLEN + PLEN) + (HLEN + t)) * CC * 13;
        for (int idx = tid; idx < CC * 13; idx += 256) {
            int c = idx / 13, f = idx - c * 13;
            xs[c][2 + f] = ft[idx];
        }
        __syncthreads();

        // ---- gated graph MLP: g[j] = sigm(b + x1flat . W_mlp[:,j]) ----
        if (tid < CC) {
            float a0 = b_mlp[tid], a1 = 0.f, a2 = 0.f, a3 = 0.f;
            const float* w = W_mlp + tid;
            #pragma unroll 1
            for (int c = 0; c < CC; ++c) {
                #pragma unroll
                for (int f = 0; f < IND; ++f) {
                    float p = xs[c][1 + f] * w[f * CC];
                    if ((f & 3) == 0)      a0 += p;
                    else if ((f & 3) == 1) a1 += p;
                    else if ((f & 3) == 2) a2 += p;
                    else                   a3 += p;
                }
                w += IND * CC;
            }
            xs[tid][0] = sigm(a0 + a1 + a2 + a3);
        }
        __syncthreads();

        // ---- u = mean over cities of [g, xn, feat] ----
        if (tid < DD) {
            float a0 = 0.f, a1 = 0.f, a2 = 0.f, a3 = 0.f;
            for (int c = 0; c < CC; c += 4) {
                a0 += xs[c][tid]; a1 += xs[c + 1][tid];
                a2 += xs[c + 2][tid]; a3 += xs[c + 3][tid];
            }
            ubuf[tid] = (a0 + a1 + a2 + a3) * (1.0f / CC);
        }
        __syncthreads();

        // ---- GRU gates ----
        if (tid < 96) {
            float a = b_ih_g[tid];
            #pragma unroll
            for (int k = 0; k < DD; ++k) a += ubuf[k] * Wih_g[k * 96 + tid];
            gxbuf[tid] = a;
        }
        for (int idx = tid; idx < 4 * 96; idx += 256) {
            int l = idx / 96, j = idx - l * 96;
            float a = b_hh_g[j];
            #pragma unroll
            for (int k = 0; k < HB; ++k) a += hn[l][k] * Whh_g[k * 96 + j];
            ghbuf[l][j] = a;
        }
        __syncthreads();
        if (tid < 128) {
            int l = tid >> 5, k = tid & 31;
            float r = sigm(gxbuf[k] + ghbuf[l][k]);
            float z = sigm(gxbuf[HB + k] + ghbuf[l][HB + k]);
            float n = tanhx(gxbuf[2 * HB + k] + r * ghbuf[l][2 * HB + k]);
            hn[l][k] = (1.0f - z) * n + z * hn[l][k];
        }
        __syncthreads();

        // ==== BiLSTM layer 0 over cities ====
        {
            const int row = d * 128 + gi;
            #pragma unroll
            for (int k = 0; k < DD; ++k) wreg[k] = Wih0[row * DD + k];
            #pragma unroll
            for (int k = 0; k < HB; ++k) whreg[k] = Whh0[row * HB + k];
            breg = b0[row];
        }
        if (tid < 64) {
            hcur[dd][kk] = hn[dd][kk];
            creg = cn[dd][kk];
        }
        __syncthreads();

        #pragma unroll 1
        for (int ci = 0; ci < CC; ++ci) {
            const int xc = d ? (CC - 1 - ci) : ci;
            float a0 = breg, a1 = 0.f, a2 = 0.f, a3 = 0.f;
            #pragma unroll
            for (int k = 0; k < DD; ++k) {
                float p = xs[xc][k] * wreg[k];
                if ((k & 3) == 0)      a0 += p;
                else if ((k & 3) == 1) a1 += p;
                else if ((k & 3) == 2) a2 += p;
                else                   a3 += p;
            }
            #pragma unroll
            for (int k = 0; k < HB; ++k) {
                float p = hcur[d][k] * whreg[k];
                if ((k & 3) == 0)      a0 += p;
                else if ((k & 3) == 1) a1 += p;
                else if ((k & 3) == 2) a2 += p;
                else                   a3 += p;
            }
            gates[d][gi] = a0 + a1 + a2 + a3;
            __syncthreads();
            if (tid < 64) {
                const int xc2 = dd ? (CC - 1 - ci) : ci;
                float iv = sigm(gates[dd][kk]);
                float fv = sigm(gates[dd][HB + kk]);
                float gv = tanhx(gates[dd][2 * HB + kk]);
                float ov = sigm(gates[dd][3 * HB + kk]);
                creg = fv * creg + iv * gv;
                float hv = ov * tanhx(creg);
                hcur[dd][kk] = hv;
                y0buf[xc2][dd * HB + kk] = hv;
            }
            __syncthreads();
        }
        if (tid < 64) {
            hn[dd][kk] = hcur[dd][kk];
            cn[dd][kk] = creg;
        }
        __syncthreads();

        // ==== BiLSTM layer 1 over layer-0 outputs ====
        {
            const int row = d * 128 + gi;
            #pragma unroll
            for (int k = 0; k < 2 * HB; ++k) wreg[k] = Wih1[row * 2 * HB + k];
            #pragma unroll
            for (int k = 0; k < HB; ++k) whreg[k] = Whh1[row * HB + k];
            breg = b1[row];
        }
        if (tid < 64) {
            hcur[dd][kk] = hn[2 + dd][kk];
            creg = cn[2 + dd][kk];
        }
        __syncthreads();

        const float wfc = (tid < 64) ? W_fc[kk] : 0.f;
        const float bfc = b_fc[0];

        #pragma unroll 1
        for (int ci = 0; ci < CC; ++ci) {
            const int xc = d ? (CC - 1 - ci) : ci;
            float a0 = breg, a1 = 0.f, a2 = 0.f, a3 = 0.f;
            #pragma unroll
            for (int k = 0; k < 2 * HB; ++k) {
                float p = y0buf[xc][k] * wreg[k];
                if ((k & 3) == 0)      a0 += p;
                else if ((k & 3) == 1) a1 += p;
                else if ((k & 3) == 2) a2 += p;
                else                   a3 += p;
            }
            #pragma unroll
            for (int k = 0; k < HB; ++k) {
                float p = hcur[d][k] * whreg[k];
                if ((k & 3) == 0)      a0 += p;
                else if ((k & 3) == 1) a1 += p;
                else if ((k & 3) == 2) a2 += p;
                else                   a3 += p;
            }
            gates[d][gi] = a0 + a1 + a2 + a3;
            __syncthreads();
            if (tid < 64) {
                float iv = sigm(gates[dd][kk]);
                float fv = sigm(gates[dd][HB + kk]);
                float gv = tanhx(gates[dd][2 * HB + kk]);
                float ov = sigm(gates[dd][3 * HB + kk]);
                creg = fv * creg + iv * gv;
                float hv = ov * tanhx(creg);
                hcur[dd][kk] = hv;
                // forward direction feeds the FC head: xn[ci] = yf1[ci] . W_fc + b_fc
                float contrib = hv * wfc;
                contrib += __shfl_xor(contrib, 16);
                contrib += __shfl_xor(contrib, 8);
                contrib += __shfl_xor(contrib, 4);
                contrib += __shfl_xor(contrib, 2);
                contrib += __shfl_xor(contrib, 1);
                if (tid == 0) {
                    float xnv = contrib + bfc;
                    xn_lds[ci] = xnv;
                    out[((size_t)b * PLEN + t) * CC + ci] = xnv;
                }
            }
            __syncthreads();
        }
        if (tid < 64) {
            hn[2 + dd][kk] = hcur[dd][kk];
            cn[2 + dd][kk] = creg;
        }
        __syncthreads();
        for (int c = tid; c < CC; c += 256) xs[c][1] = xn_lds[c];
        __syncthreads();
    }
}

extern "C" void kernel_launch(void* const* d_in, const int* in_sizes, int n_in,
                              void* d_out, int out_size, void* d_ws, size_t ws_size,
                              hipStream_t stream) {
    const float* rain_hist = (const float*)d_in[0];
    const float* feature   = (const float*)d_in[1];
    const float* h0        = (const float*)d_in[2];
    const float* c0        = (const float*)d_in[3];
    const float* W_mlp     = (const float*)d_in[4];
    const float* b_mlp     = (const float*)d_in[5];
    const float* Wih_g     = (const float*)d_in[6];
    const float* Whh_g     = (const float*)d_in[7];
    const float* b_ih_g    = (const float*)d_in[8];
    const float* b_hh_g    = (const float*)d_in[9];
    const float* Wih0      = (const float*)d_in[10];
    const float* Whh0      = (const float*)d_in[11];
    const float* b0        = (const float*)d_in[12];
    const float* Wih1      = (const float*)d_in[13];
    const float* Whh1      = (const float*)d_in[14];
    const float* b1        = (const float*)d_in[15];
    const float* W_fc      = (const float*)d_in[16];
    const float* b_fc      = (const float*)d_in[17];
    float* out = (float*)d_out;

    bilstm_kernel<<<dim3(BB), dim3(256), 0, stream>>>(
        rain_hist, feature, h0, c0, W_mlp, b_mlp, Wih_g, Whh_g, b_ih_g, b_hh_g,
        Wih0, Whh0, b0, Wih1, Whh1, b1, W_fc, b_fc, out);
}